// Round 2
// baseline (938.876 us; speedup 1.0000x reference)
//
#include <hip/hip_runtime.h>
#include <hip/hip_bf16.h>

#define NPTS   2048
#define IDIM   16
#define HDIM   32
#define CUTSN  8
#define EPSV   1e-5f
#define PSCALE 0.07856742013183862f   /* 1/(sqrt(2)*9) */

#define BI 64      /* i-rows per block (one per lane) */
#define BJ 128     /* j-cols per block */
#define PWT 512    /* threads: 8 waves, each wave gets 16 j */

__device__ __forceinline__ float leaky(float x) { return x >= 0.f ? x : 0.2f * x; }

/* =================== fused pre-kernel: net_in + GroupNorm ===================
 * 4 blocks (one per group) x 1024 threads; each thread handles rows t, t+1024.
 * Each block computes layer1 fully (redundant) + its 8 layer-2 channels,
 * block-reduces stats, normalizes, writes its fin columns. Also zeros fout. */
__global__ __launch_bounds__(1024, 4) void fused_in_kernel(
    const float* __restrict__ features,
    const float* __restrict__ W1, const float* __restrict__ b1,
    const float* __restrict__ W2, const float* __restrict__ b2,
    const float* __restrict__ gw, const float* __restrict__ gb,
    float* __restrict__ fin, float* __restrict__ fout)
{
    const int g = blockIdx.x;
    const int t = threadIdx.x;

    __shared__ __align__(16) float sW1[HDIM * IDIM];   /* 512 */
    __shared__ __align__(16) float sW2[8 * HDIM];      /* 256: rows g*8.. */
    __shared__ float sb1[HDIM], sb2[8], sgw[8], sgb[8];
    __shared__ float ls[16], lss[16], smu, srs;

    if (t < HDIM * IDIM) sW1[t] = W1[t];
    if (t < 8 * HDIM)    sW2[t] = W2[(g * 8) * HDIM + t];
    if (t < HDIM)        sb1[t] = b1[t];
    if (t < 8)  { sb2[t] = b2[g * 8 + t]; sgw[t] = gw[g * 8 + t]; sgb[t] = gb[g * 8 + t]; }
    /* zero this block's quarter of fout */
#pragma unroll
    for (int e = 0; e < 4; ++e)
        *(float4*)&fout[g * 16384 + t * 16 + e * 4] = make_float4(0.f, 0.f, 0.f, 0.f);
    __syncthreads();

    float z[2][8];
    float sum = 0.f, ss = 0.f;
#pragma unroll
    for (int rr = 0; rr < 2; ++rr) {
        const int r = t + rr * 1024;
        float x[IDIM];
#pragma unroll
        for (int e = 0; e < 4; ++e)
            *(float4*)&x[e * 4] = *(const float4*)&features[r * IDIM + e * 4];
        float y[HDIM];
#pragma unroll
        for (int h = 0; h < HDIM; ++h) {
            float v = sb1[h];
#pragma unroll
            for (int k = 0; k < IDIM; ++k) v = fmaf(x[k], sW1[h * IDIM + k], v);
            y[h] = leaky(v);
        }
#pragma unroll
        for (int c = 0; c < 8; ++c) {
            float v = sb2[c];
#pragma unroll
            for (int k = 0; k < HDIM; ++k) v = fmaf(y[k], sW2[c * HDIM + k], v);
            v = leaky(v);
            z[rr][c] = v;
            sum += v; ss = fmaf(v, v, ss);
        }
    }
    /* block reduction over 16 waves */
#pragma unroll
    for (int off = 32; off; off >>= 1) {
        sum += __shfl_down(sum, off, 64);
        ss  += __shfl_down(ss,  off, 64);
    }
    const int wv = t >> 6, ln = t & 63;
    if (ln == 0) { ls[wv] = sum; lss[wv] = ss; }
    __syncthreads();
    if (t == 0) {
        float s = 0.f, q = 0.f;
#pragma unroll
        for (int w = 0; w < 16; ++w) { s += ls[w]; q += lss[w]; }
        const float inv = 1.f / (8.f * NPTS);
        const float mu = s * inv;
        smu = mu;
        srs = rsqrtf(q * inv - mu * mu + EPSV);
    }
    __syncthreads();
    const float mu = smu, rs = srs;
#pragma unroll
    for (int rr = 0; rr < 2; ++rr) {
        const int r = t + rr * 1024;
        float o[8];
#pragma unroll
        for (int c = 0; c < 8; ++c)
            o[c] = fmaf((z[rr][c] - mu) * rs, sgw[c], sgb[c]);
        *(float4*)&fin[r * HDIM + g * 8]     = *(float4*)&o[0];
        *(float4*)&fin[r * HDIM + g * 8 + 4] = *(float4*)&o[4];
    }
}

/* =================== fused post-kernel: net_out + GroupNorm =================== */
__global__ __launch_bounds__(1024, 4) void fused_out_kernel(
    const float* __restrict__ fsum,
    const float* __restrict__ W1, const float* __restrict__ b1,
    const float* __restrict__ W2, const float* __restrict__ b2,
    const float* __restrict__ gw, const float* __restrict__ gb,
    float* __restrict__ out)
{
    const int g = blockIdx.x;
    const int t = threadIdx.x;

    __shared__ __align__(16) float sW1[HDIM * HDIM];   /* 1024 */
    __shared__ __align__(16) float sW2[8 * HDIM];      /* 256 */
    __shared__ float sb1[HDIM], sb2[8], sgw[8], sgb[8];
    __shared__ float ls[16], lss[16], smu, srs;

    sW1[t] = W1[t];
    if (t < 8 * HDIM) sW2[t] = W2[(g * 8) * HDIM + t];
    if (t < HDIM)     sb1[t] = b1[t];
    if (t < 8) { sb2[t] = b2[g * 8 + t]; sgw[t] = gw[g * 8 + t]; sgb[t] = gb[g * 8 + t]; }
    __syncthreads();

    float z[2][8];
    float sum = 0.f, ss = 0.f;
#pragma unroll
    for (int rr = 0; rr < 2; ++rr) {
        const int r = t + rr * 1024;
        float x[HDIM];
#pragma unroll
        for (int e = 0; e < 8; ++e)
            *(float4*)&x[e * 4] = *(const float4*)&fsum[r * HDIM + e * 4];
        float y[HDIM];
#pragma unroll
        for (int h = 0; h < HDIM; ++h) {
            float v = sb1[h];
#pragma unroll
            for (int k = 0; k < HDIM; ++k) v = fmaf(x[k], sW1[h * HDIM + k], v);
            y[h] = leaky(v);
        }
#pragma unroll
        for (int c = 0; c < 8; ++c) {
            float v = sb2[c];
#pragma unroll
            for (int k = 0; k < HDIM; ++k) v = fmaf(y[k], sW2[c * HDIM + k], v);
            v = leaky(v);
            z[rr][c] = v;
            sum += v; ss = fmaf(v, v, ss);
        }
    }
#pragma unroll
    for (int off = 32; off; off >>= 1) {
        sum += __shfl_down(sum, off, 64);
        ss  += __shfl_down(ss,  off, 64);
    }
    const int wv = t >> 6, ln = t & 63;
    if (ln == 0) { ls[wv] = sum; lss[wv] = ss; }
    __syncthreads();
    if (t == 0) {
        float s = 0.f, q = 0.f;
#pragma unroll
        for (int w = 0; w < 16; ++w) { s += ls[w]; q += lss[w]; }
        const float inv = 1.f / (8.f * NPTS);
        const float mu = s * inv;
        smu = mu;
        srs = rsqrtf(q * inv - mu * mu + EPSV);
    }
    __syncthreads();
    const float mu = smu, rs = srs;
#pragma unroll
    for (int rr = 0; rr < 2; ++rr) {
        const int r = t + rr * 1024;
        float o[8];
#pragma unroll
        for (int c = 0; c < 8; ++c)
            o[c] = fmaf((z[rr][c] - mu) * rs, sgw[c], sgb[c]);
        *(float4*)&out[r * HDIM + g * 8]     = *(float4*)&o[0];
        *(float4*)&out[r * HDIM + g * 8 + 4] = *(float4*)&o[4];
    }
}

/* =================== the N^2 pairwise kernel (LDS-staged) ===================
 * grid (16, 32): x -> 128-j tile, y -> 64-i tile. 512 threads = 8 waves.
 * lane = i; wave w owns j-subrange [w*16, w*16+16), processed in chunks of 4.
 * ALL inner-loop operands live in LDS; reads are wave-uniform -> broadcast. */
__global__ __launch_bounds__(PWT, 4) void pairwise_kernel(
    const float* __restrict__ points, const float* __restrict__ nuv,
    const float* __restrict__ A1, const float* __restrict__ B1,
    const float* __restrict__ A2, const float* __restrict__ B2,
    const float* __restrict__ fin, float* __restrict__ fout)
{
    const int t    = threadIdx.x;
    const int lane = t & 63;
    const int wave = __builtin_amdgcn_readfirstlane(t >> 6);
    const int i     = blockIdx.y * BI + lane;
    const int jbase = blockIdx.x * BJ;

    /* f-tile transposed: sfT[h][j], padded to 132 so rows stay 16B-aligned */
    __shared__ __align__(16) float sfT[HDIM][132];
    __shared__ __align__(16) float sp[BJ][8];        /* x,y,z,nx,ny,nz,-,- */
    __shared__ __align__(16) float sA2P[HDIM][12];   /* A2 row(8) + B2 + pad */
    __shared__ __align__(16) float sA1B1[CUTSN][4];  /* A1 row(3) + B1 */
    __shared__ float red[8][64][9];                  /* stride 9: conflict-free */

    /* ---- stage ---- */
    {
        const float4* src4 = (const float4*)(fin + jbase * HDIM);
#pragma unroll
        for (int s = 0; s < 2; ++s) {
            const int idx4 = t + s * PWT;            /* < 1024 */
            float4 v = src4[idx4];
            const int flat = idx4 * 4;
            const int j = flat >> 5, h = flat & 31;
            sfT[h + 0][j] = v.x; sfT[h + 1][j] = v.y;
            sfT[h + 2][j] = v.z; sfT[h + 3][j] = v.w;
        }
        if (t < BJ) {
            const int j = jbase + t;
            sp[t][0] = points[j * 3 + 0] * PSCALE;
            sp[t][1] = points[j * 3 + 1] * PSCALE;
            sp[t][2] = points[j * 3 + 2] * PSCALE;
            sp[t][3] = nuv[j * 9 + 0];
            sp[t][4] = nuv[j * 9 + 1];
            sp[t][5] = nuv[j * 9 + 2];
            sp[t][6] = 0.f; sp[t][7] = 0.f;
        }
        if (t < 384) {
            const int r = t / 12, c = t - r * 12;
            (&sA2P[0][0])[t] = (c < 8) ? A2[r * 8 + c] : ((c == 8) ? B2[r] : 0.f);
        }
        if (t < CUTSN) {
            sA1B1[t][0] = A1[t * 3 + 0];
            sA1B1[t][1] = A1[t * 3 + 1];
            sA1B1[t][2] = A1[t * 3 + 2];
            sA1B1[t][3] = B1[t];
        }
    }

    /* ---- i-side (per lane) ---- */
    const float pix = points[i * 3 + 0] * PSCALE;
    const float piy = points[i * 3 + 1] * PSCALE;
    const float piz = points[i * 3 + 2] * PSCALE;
    float nv[9];
#pragma unroll
    for (int k = 0; k < 9; ++k) nv[k] = nuv[i * 9 + k];

    float acc[HDIM];
#pragma unroll
    for (int h = 0; h < HDIM; ++h) acc[h] = 0.f;

    __syncthreads();

    const int jw0 = wave * 16;
#pragma unroll 1
    for (int cc = 0; cc < 4; ++cc) {
        const int jb4 = jw0 + cc * 4;

        /* phase A: geometry + first layer for 4 j's */
        float X[4][3], wq[4];
#pragma unroll
        for (int q = 0; q < 4; ++q) {
            const int jl = jb4 + q;
            const float4 p0 = *(const float4*)&sp[jl][0];
            const float4 p1 = *(const float4*)&sp[jl][4];
            const float dx = p0.x - pix, dy = p0.y - piy, dz = p0.z - piz;
            const float sq = fmaf(dx, dx, fmaf(dy, dy, dz * dz));
            const float dot = fmaf(nv[0], p0.w, fmaf(nv[1], p1.x, nv[2] * p1.y));
            const float tt = 2.f - dot;
            wq[q] = __expf(-sq * tt * tt);
            X[q][0] = fmaf(nv[0], dx, fmaf(nv[1], dy, nv[2] * dz));
            X[q][1] = fmaf(nv[3], dx, fmaf(nv[4], dy, nv[5] * dz));
            X[q][2] = fmaf(nv[6], dx, fmaf(nv[7], dy, nv[8] * dz));
        }
        float u[4][CUTSN];
#pragma unroll
        for (int c = 0; c < CUTSN; ++c) {
            const float4 ab = *(const float4*)&sA1B1[c][0];
#pragma unroll
            for (int q = 0; q < 4; ++q)
                u[q][c] = fmaxf(fmaf(X[q][0], ab.x,
                               fmaf(X[q][1], ab.y,
                               fmaf(X[q][2], ab.z, ab.w))), 0.f);
        }

        /* phase B: 8->32 matvec + window*fin accumulate, h outer */
#pragma unroll
        for (int h = 0; h < HDIM; ++h) {
            const float4 a2a = *(const float4*)&sA2P[h][0];
            const float4 a2b = *(const float4*)&sA2P[h][4];
            const float  b2h = sA2P[h][8];
            const float4 f4  = *(const float4*)&sfT[h][jb4];
            const float fv[4] = { f4.x, f4.y, f4.z, f4.w };
            float a = acc[h];
#pragma unroll
            for (int q = 0; q < 4; ++q) {
                float v = fmaf(u[q][0], a2a.x, fmaf(u[q][1], a2a.y,
                          fmaf(u[q][2], a2a.z, fmaf(u[q][3], a2a.w,
                          fmaf(u[q][4], a2b.x, fmaf(u[q][5], a2b.y,
                          fmaf(u[q][6], a2b.z, fmaf(u[q][7], a2b.w, b2h))))))));
                v = fmaxf(v, 0.f);
                a = fmaf(v, wq[q] * fv[q], a);
            }
            acc[h] = a;
        }
    }

    /* ---- cross-wave reduction in 4 rounds of 8 h, then atomics ---- */
#pragma unroll 1
    for (int r4 = 0; r4 < 4; ++r4) {
        const int h0 = r4 * 8;
        __syncthreads();
#pragma unroll
        for (int c = 0; c < 8; ++c) red[wave][lane][c] = acc[h0 + c];
        __syncthreads();
        {
            const int il = t >> 3, hh = t & 7;     /* t<512 -> 512 cells */
            float v = 0.f;
#pragma unroll
            for (int w = 0; w < 8; ++w) v += red[w][il][hh];
            atomicAdd(&fout[(blockIdx.y * BI + il) * HDIM + h0 + hh], v);
        }
    }
}

extern "C" void kernel_launch(void* const* d_in, const int* in_sizes, int n_in,
                              void* d_out, int out_size, void* d_ws, size_t ws_size,
                              hipStream_t stream)
{
    const float* points   = (const float*)d_in[0];
    const float* nuv      = (const float*)d_in[1];
    const float* features = (const float*)d_in[2];
    const float* W_in1    = (const float*)d_in[3];
    const float* b_in1    = (const float*)d_in[4];
    const float* W_in2    = (const float*)d_in[5];
    const float* b_in2    = (const float*)d_in[6];
    const float* g_in_w   = (const float*)d_in[7];
    const float* g_in_b   = (const float*)d_in[8];
    const float* A1       = (const float*)d_in[9];
    const float* A2       = (const float*)d_in[10];
    const float* W_out1   = (const float*)d_in[11];
    const float* b_out1   = (const float*)d_in[12];
    const float* W_out2   = (const float*)d_in[13];
    const float* b_out2   = (const float*)d_in[14];
    const float* g_out_w  = (const float*)d_in[15];
    const float* g_out_b  = (const float*)d_in[16];
    const float* B1       = (const float*)d_in[17];
    const float* B2       = (const float*)d_in[18];

    float* ws  = (float*)d_ws;
    float* fin  = ws;            /* N*H = 65536 floats */
    float* fout = ws + 65536;    /* N*H */
    float* out  = (float*)d_out;

    fused_in_kernel<<<dim3(4), dim3(1024), 0, stream>>>(
        features, W_in1, b_in1, W_in2, b_in2, g_in_w, g_in_b, fin, fout);

    pairwise_kernel<<<dim3(NPTS / BJ, NPTS / BI), dim3(PWT), 0, stream>>>(
        points, nuv, A1, B1, A2, B2, fin, fout);

    fused_out_kernel<<<dim3(4), dim3(1024), 0, stream>>>(
        fout, W_out1, b_out1, W_out2, b_out2, g_out_w, g_out_b, out);
}

// Round 3
// 483.413 us; speedup vs baseline: 1.9422x; 1.9422x over previous
//
#include <hip/hip_runtime.h>
#include <hip/hip_bf16.h>

#define NPTS   2048
#define IDIM   16
#define HDIM   32
#define CUTSN  8
#define EPSV   1e-5f
#define PSCALE 0.07856742013183862f   /* 1/(sqrt(2)*9) */

#define BI 64      /* i-rows per block (one per lane) */
#define BJ 128     /* j-cols per block */
#define PWT 512    /* threads: 8 waves, each wave owns 16 j */

__device__ __forceinline__ float leaky(float x) { return x >= 0.f ? x : 0.2f * x; }

/* ---------------- two-layer MLP (per-row), K = input dim ---------------- */
template <int K>
__global__ __launch_bounds__(256) void net2_kernel(
    const float* __restrict__ xin,
    const float* __restrict__ W1, const float* __restrict__ b1,
    const float* __restrict__ W2, const float* __restrict__ b2,
    float* __restrict__ out)
{
    int i = blockIdx.x * 256 + threadIdx.x;   // row
    float x[K];
#pragma unroll
    for (int k = 0; k < K; ++k) x[k] = xin[i * K + k];

    float y[HDIM];
#pragma unroll
    for (int h = 0; h < HDIM; ++h) {
        float v = b1[h];
#pragma unroll
        for (int k = 0; k < K; ++k) v = fmaf(x[k], W1[h * K + k], v);
        y[h] = leaky(v);
    }
#pragma unroll
    for (int h = 0; h < HDIM; ++h) {
        float v = b2[h];
#pragma unroll
        for (int k = 0; k < HDIM; ++k) v = fmaf(y[k], W2[h * HDIM + k], v);
        out[i * HDIM + h] = leaky(v);
    }
}

/* ---------------- GroupNorm stats: one block per group ---------------- */
__global__ __launch_bounds__(256) void gn_stats_kernel(
    const float* __restrict__ x, float* __restrict__ stats /* mu[4], rs[4] */)
{
    int g = blockIdx.x;
    float sum = 0.f, ss = 0.f;
    for (int i = threadIdx.x; i < NPTS; i += 256) {
        const float* p = x + i * HDIM + g * 8;
#pragma unroll
        for (int c = 0; c < 8; ++c) { float v = p[c]; sum += v; ss = fmaf(v, v, ss); }
    }
#pragma unroll
    for (int off = 32; off; off >>= 1) {
        sum += __shfl_down(sum, off, 64);
        ss  += __shfl_down(ss,  off, 64);
    }
    __shared__ float ls[4], lss[4];
    int wv = threadIdx.x >> 6, ln = threadIdx.x & 63;
    if (ln == 0) { ls[wv] = sum; lss[wv] = ss; }
    __syncthreads();
    if (threadIdx.x == 0) {
        float s = ls[0] + ls[1] + ls[2] + ls[3];
        float q = lss[0] + lss[1] + lss[2] + lss[3];
        float inv = 1.f / (8.f * NPTS);
        float mu = s * inv;
        float var = q * inv - mu * mu;
        stats[g]     = mu;
        stats[4 + g] = rsqrtf(var + EPSV);
    }
}

/* ------------- GroupNorm apply (+ optional zero of another buffer) ------------- */
__global__ __launch_bounds__(256) void gn_apply_kernel(
    const float* __restrict__ x, const float* __restrict__ stats,
    const float* __restrict__ gw, const float* __restrict__ gb,
    float* __restrict__ out, float* __restrict__ zbuf)
{
    int idx = blockIdx.x * 256 + threadIdx.x;   // < NPTS*HDIM
    int c = idx & (HDIM - 1);
    int g = c >> 3;
    out[idx] = fmaf((x[idx] - stats[g]) * stats[4 + g], gw[c], gb[c]);
    if (zbuf) zbuf[idx] = 0.f;
}

/* =================== the N^2 pairwise kernel (LDS-staged) ===================
 * grid (16, 32): x -> 128-j tile, y -> 64-i tile. 512 threads = 8 waves.
 * lane = i; wave w owns j-subrange [w*16, w*16+16), processed in chunks of 4.
 * ALL inner-loop operands live in LDS; j-side reads are wave-uniform ->
 * broadcast ds_read. acc[] / u[] use ONLY compile-time indices (rule #20). */
__global__ __launch_bounds__(PWT, 4) void pairwise_kernel(
    const float* __restrict__ points, const float* __restrict__ nuv,
    const float* __restrict__ A1, const float* __restrict__ B1,
    const float* __restrict__ A2, const float* __restrict__ B2,
    const float* __restrict__ fin, float* __restrict__ fout)
{
    const int t    = threadIdx.x;
    const int lane = t & 63;
    const int wave = __builtin_amdgcn_readfirstlane(t >> 6);
    const int i     = blockIdx.y * BI + lane;
    const int jbase = blockIdx.x * BJ;

    /* f-tile transposed: sfT[h][j], padded to 132 so rows stay 16B-aligned */
    __shared__ __align__(16) float sfT[HDIM][132];
    __shared__ __align__(16) float sp[BJ][8];        /* x,y,z,nx,ny,nz,-,- */
    __shared__ __align__(16) float sA2P[HDIM][12];   /* A2 row(8) + B2 + pad */
    __shared__ __align__(16) float sA1B1[CUTSN][4];  /* A1 row(3) + B1 */
    __shared__ float red[8][64][9];                  /* stride 9: conflict-free */

    /* ---- stage ---- */
    {
        const float4* src4 = (const float4*)(fin + jbase * HDIM);
#pragma unroll
        for (int s = 0; s < 2; ++s) {
            const int idx4 = t + s * PWT;            /* < 1024 */
            float4 v = src4[idx4];
            const int flat = idx4 * 4;
            const int j = flat >> 5, h = flat & 31;
            sfT[h + 0][j] = v.x; sfT[h + 1][j] = v.y;
            sfT[h + 2][j] = v.z; sfT[h + 3][j] = v.w;
        }
        if (t < BJ) {
            const int j = jbase + t;
            sp[t][0] = points[j * 3 + 0] * PSCALE;
            sp[t][1] = points[j * 3 + 1] * PSCALE;
            sp[t][2] = points[j * 3 + 2] * PSCALE;
            sp[t][3] = nuv[j * 9 + 0];
            sp[t][4] = nuv[j * 9 + 1];
            sp[t][5] = nuv[j * 9 + 2];
            sp[t][6] = 0.f; sp[t][7] = 0.f;
        }
        if (t < 384) {
            const int r = t / 12, c = t - r * 12;
            (&sA2P[0][0])[t] = (c < 8) ? A2[r * 8 + c] : ((c == 8) ? B2[r] : 0.f);
        }
        if (t < CUTSN) {
            sA1B1[t][0] = A1[t * 3 + 0];
            sA1B1[t][1] = A1[t * 3 + 1];
            sA1B1[t][2] = A1[t * 3 + 2];
            sA1B1[t][3] = B1[t];
        }
    }

    /* ---- i-side (per lane) ---- */
    const float pix = points[i * 3 + 0] * PSCALE;
    const float piy = points[i * 3 + 1] * PSCALE;
    const float piz = points[i * 3 + 2] * PSCALE;
    float nv[9];
#pragma unroll
    for (int k = 0; k < 9; ++k) nv[k] = nuv[i * 9 + k];

    float acc[HDIM];
#pragma unroll
    for (int h = 0; h < HDIM; ++h) acc[h] = 0.f;

    __syncthreads();

    const int jw0 = wave * 16;
#pragma unroll 1
    for (int cc = 0; cc < 4; ++cc) {
        const int jb4 = jw0 + cc * 4;

        /* phase A: geometry + first layer for 4 j's; fold window into u
         * (w > 0, so w*relu(y) = relu(w*y)) */
        float X[4][3], wq[4];
#pragma unroll
        for (int q = 0; q < 4; ++q) {
            const int jl = jb4 + q;
            const float4 p0 = *(const float4*)&sp[jl][0];
            const float4 p1 = *(const float4*)&sp[jl][4];
            const float dx = p0.x - pix, dy = p0.y - piy, dz = p0.z - piz;
            const float sq = fmaf(dx, dx, fmaf(dy, dy, dz * dz));
            const float dot = fmaf(nv[0], p0.w, fmaf(nv[1], p1.x, nv[2] * p1.y));
            const float tt = 2.f - dot;
            wq[q] = __expf(-sq * tt * tt);
            X[q][0] = fmaf(nv[0], dx, fmaf(nv[1], dy, nv[2] * dz));
            X[q][1] = fmaf(nv[3], dx, fmaf(nv[4], dy, nv[5] * dz));
            X[q][2] = fmaf(nv[6], dx, fmaf(nv[7], dy, nv[8] * dz));
        }
        float u[4][CUTSN];
#pragma unroll
        for (int c = 0; c < CUTSN; ++c) {
            const float4 ab = *(const float4*)&sA1B1[c][0];
#pragma unroll
            for (int q = 0; q < 4; ++q) {
                float v = fmaf(X[q][0], ab.x,
                          fmaf(X[q][1], ab.y,
                          fmaf(X[q][2], ab.z, ab.w)));
                u[q][c] = wq[q] * fmaxf(v, 0.f);     /* window folded in */
            }
        }

        /* phase B: 8->32 matvec + fin accumulate, h outer */
#pragma unroll
        for (int h = 0; h < HDIM; ++h) {
            const float4 a2a = *(const float4*)&sA2P[h][0];
            const float4 a2b = *(const float4*)&sA2P[h][4];
            const float  b2h = sA2P[h][8];
            const float4 f4  = *(const float4*)&sfT[h][jb4];
            const float fv[4] = { f4.x, f4.y, f4.z, f4.w };
            float a = acc[h];
#pragma unroll
            for (int q = 0; q < 4; ++q) {
                float v = fmaf(u[q][0], a2a.x, fmaf(u[q][1], a2a.y,
                          fmaf(u[q][2], a2a.z, fmaf(u[q][3], a2a.w,
                          fmaf(u[q][4], a2b.x, fmaf(u[q][5], a2b.y,
                          fmaf(u[q][6], a2b.z, fmaf(u[q][7], a2b.w,
                               wq[q] * b2h))))))));
                a = fmaf(fmaxf(v, 0.f), fv[q], a);
            }
            acc[h] = a;
        }
    }

    /* ---- cross-wave reduction, 4 FULLY-UNROLLED rounds of 8 h ----
     * (h0 must be compile-time: a runtime index into acc[] demotes the
     *  whole array to scratch -> 1.3 GB of spill traffic; see round 2) */
#pragma unroll
    for (int r4 = 0; r4 < 4; ++r4) {
        const int h0 = r4 * 8;                      /* static after unroll */
        __syncthreads();
#pragma unroll
        for (int c = 0; c < 8; ++c) red[wave][lane][c] = acc[h0 + c];
        __syncthreads();
        {
            const int il = t >> 3, hh = t & 7;      /* 512 cells = 64 i x 8 h */
            float v = 0.f;
#pragma unroll
            for (int w = 0; w < 8; ++w) v += red[w][il][hh];
            atomicAdd(&fout[(blockIdx.y * BI + il) * HDIM + h0 + hh], v);
        }
    }
}

extern "C" void kernel_launch(void* const* d_in, const int* in_sizes, int n_in,
                              void* d_out, int out_size, void* d_ws, size_t ws_size,
                              hipStream_t stream)
{
    const float* points   = (const float*)d_in[0];
    const float* nuv      = (const float*)d_in[1];
    const float* features = (const float*)d_in[2];
    const float* W_in1    = (const float*)d_in[3];
    const float* b_in1    = (const float*)d_in[4];
    const float* W_in2    = (const float*)d_in[5];
    const float* b_in2    = (const float*)d_in[6];
    const float* g_in_w   = (const float*)d_in[7];
    const float* g_in_b   = (const float*)d_in[8];
    const float* A1       = (const float*)d_in[9];
    const float* A2       = (const float*)d_in[10];
    const float* W_out1   = (const float*)d_in[11];
    const float* b_out1   = (const float*)d_in[12];
    const float* W_out2   = (const float*)d_in[13];
    const float* b_out2   = (const float*)d_in[14];
    const float* g_out_w  = (const float*)d_in[15];
    const float* g_out_b  = (const float*)d_in[16];
    const float* B1       = (const float*)d_in[17];
    const float* B2       = (const float*)d_in[18];

    float* ws     = (float*)d_ws;
    float* t2a    = ws;              /* N*H = 65536 */
    float* fin    = ws + 65536;
    float* t2b    = ws + 131072;
    float* fout   = ws + 196608;
    float* stats1 = ws + 262144;     /* 8 floats */
    float* stats2 = ws + 262152;     /* 8 floats */
    float* out    = (float*)d_out;

    /* net_in */
    net2_kernel<IDIM><<<dim3(NPTS / 256), dim3(256), 0, stream>>>(
        features, W_in1, b_in1, W_in2, b_in2, t2a);
    gn_stats_kernel<<<dim3(4), dim3(256), 0, stream>>>(t2a, stats1);
    gn_apply_kernel<<<dim3(NPTS * HDIM / 256), dim3(256), 0, stream>>>(
        t2a, stats1, g_in_w, g_in_b, fin, fout);

    /* all-pairs interaction */
    pairwise_kernel<<<dim3(NPTS / BJ, NPTS / BI), dim3(PWT), 0, stream>>>(
        points, nuv, A1, B1, A2, B2, fin, fout);

    /* net_out */
    net2_kernel<HDIM><<<dim3(NPTS / 256), dim3(256), 0, stream>>>(
        fout, W_out1, b_out1, W_out2, b_out2, t2b);
    gn_stats_kernel<<<dim3(4), dim3(256), 0, stream>>>(t2b, stats2);
    gn_apply_kernel<<<dim3(NPTS * HDIM / 256), dim3(256), 0, stream>>>(
        t2b, stats2, g_out_w, g_out_b, out, nullptr);
}

// Round 4
// 298.979 us; speedup vs baseline: 3.1403x; 1.6169x over previous
//
#include <hip/hip_runtime.h>
#include <hip/hip_bf16.h>

#define NPTS   2048
#define IDIM   16
#define HDIM   32
#define CUTSN  8
#define EPSV   1e-5f
#define PSCALE 0.07856742013183862f   /* 1/(sqrt(2)*9) */

#define BI 64      /* i-rows per block (one per lane) */
#define BJ 128     /* j-cols per block */
#define PWT 512    /* threads: 8 waves, each wave owns 16 j */

__device__ __forceinline__ float leaky(float x) { return x >= 0.f ? x : 0.2f * x; }

/* ------- two-layer MLP (per-row) + per-block GroupNorm partial sums -------
 * 8 blocks x 256 threads, one row per thread. partials layout (64 floats):
 * rows 0..3 = group sums (partials[g*8 + block]), rows 4..7 = group sumsq. */
template <int K>
__global__ __launch_bounds__(256) void net2_kernel(
    const float* __restrict__ xin,
    const float* __restrict__ W1, const float* __restrict__ b1,
    const float* __restrict__ W2, const float* __restrict__ b2,
    float* __restrict__ out, float* __restrict__ partials)
{
    const int t = threadIdx.x;
    const int i = blockIdx.x * 256 + t;
    float x[K];
#pragma unroll
    for (int k = 0; k < K; ++k) x[k] = xin[i * K + k];

    float y[HDIM];
#pragma unroll
    for (int h = 0; h < HDIM; ++h) {
        float v = b1[h];
#pragma unroll
        for (int k = 0; k < K; ++k) v = fmaf(x[k], W1[h * K + k], v);
        y[h] = leaky(v);
    }
    float ps[4]  = {0.f, 0.f, 0.f, 0.f};
    float pss[4] = {0.f, 0.f, 0.f, 0.f};
#pragma unroll
    for (int h = 0; h < HDIM; ++h) {
        float v = b2[h];
#pragma unroll
        for (int k = 0; k < HDIM; ++k) v = fmaf(y[k], W2[h * HDIM + k], v);
        v = leaky(v);
        out[i * HDIM + h] = v;
        const int g = h >> 3;                 /* compile-time after unroll */
        ps[g] += v; pss[g] = fmaf(v, v, pss[g]);
    }
    /* wave reduce the 8 partials */
#pragma unroll
    for (int off = 32; off; off >>= 1) {
#pragma unroll
        for (int g = 0; g < 4; ++g) {
            ps[g]  += __shfl_down(ps[g],  off, 64);
            pss[g] += __shfl_down(pss[g], off, 64);
        }
    }
    __shared__ float lred[4][8];
    const int wv = t >> 6, ln = t & 63;
    if (ln == 0) {
#pragma unroll
        for (int g = 0; g < 4; ++g) { lred[wv][g] = ps[g]; lred[wv][4 + g] = pss[g]; }
    }
    __syncthreads();
    if (t < 8) {
        const float v = lred[0][t] + lred[1][t] + lred[2][t] + lred[3][t];
        partials[t * 8 + blockIdx.x] = v;
    }
}

/* ------- GroupNorm apply: reduces the 8 block-partials inline ------- */
__global__ __launch_bounds__(256) void gn_apply_kernel(
    const float* __restrict__ x, const float* __restrict__ partials,
    const float* __restrict__ gw, const float* __restrict__ gb,
    float* __restrict__ out, float* __restrict__ zbuf)
{
    const int idx = blockIdx.x * 256 + threadIdx.x;   /* < NPTS*HDIM */
    const int c = idx & (HDIM - 1);
    const int g = c >> 3;
    float s = 0.f, q = 0.f;
#pragma unroll
    for (int b = 0; b < 8; ++b) {
        s += partials[g * 8 + b];
        q += partials[32 + g * 8 + b];
    }
    const float inv = 1.f / (8.f * NPTS);
    const float mu = s * inv;
    const float rs = rsqrtf(q * inv - mu * mu + EPSV);
    out[idx] = fmaf((x[idx] - mu) * rs, gw[c], gb[c]);
    if (zbuf) zbuf[idx] = 0.f;
}

/* =================== the N^2 pairwise kernel (LDS-staged) ===================
 * grid (16, 32): x -> 128-j tile, y -> 64-i tile. 512 threads = 8 waves.
 * lane = i; wave w owns j-subrange [w*16, w*16+16), processed in chunks of 4.
 * ALL inner-loop operands live in LDS; j-side reads are wave-uniform ->
 * broadcast ds_read. acc[] / u[] use ONLY compile-time indices (rule #20).
 * NO occupancy minimum in launch_bounds: a min-waves hint of 4 capped VGPRs
 * at 64 and spilled acc[] to scratch (1.1 GB HBM traffic, rounds 2-3). */
__global__ __launch_bounds__(PWT) void pairwise_kernel(
    const float* __restrict__ points, const float* __restrict__ nuv,
    const float* __restrict__ A1, const float* __restrict__ B1,
    const float* __restrict__ A2, const float* __restrict__ B2,
    const float* __restrict__ fin, float* __restrict__ fout)
{
    const int t    = threadIdx.x;
    const int lane = t & 63;
    const int wave = __builtin_amdgcn_readfirstlane(t >> 6);
    const int i     = blockIdx.y * BI + lane;
    const int jbase = blockIdx.x * BJ;

    /* f-tile transposed: sfT[h][j], padded to 132 so rows stay 16B-aligned */
    __shared__ __align__(16) float sfT[HDIM][132];
    __shared__ __align__(16) float sp[BJ][8];        /* x,y,z,nx,ny,nz,-,- */
    __shared__ __align__(16) float sA2P[HDIM][12];   /* A2 row(8) + B2 + pad */
    __shared__ __align__(16) float sA1B1[CUTSN][4];  /* A1 row(3) + B1 */
    __shared__ float red[8][64][9];                  /* stride 9: conflict-free */

    /* ---- stage ---- */
    {
        const float4* src4 = (const float4*)(fin + jbase * HDIM);
#pragma unroll
        for (int s = 0; s < 2; ++s) {
            const int idx4 = t + s * PWT;            /* < 1024 */
            float4 v = src4[idx4];
            const int flat = idx4 * 4;
            const int j = flat >> 5, h = flat & 31;
            sfT[h + 0][j] = v.x; sfT[h + 1][j] = v.y;
            sfT[h + 2][j] = v.z; sfT[h + 3][j] = v.w;
        }
        if (t < BJ) {
            const int j = jbase + t;
            sp[t][0] = points[j * 3 + 0] * PSCALE;
            sp[t][1] = points[j * 3 + 1] * PSCALE;
            sp[t][2] = points[j * 3 + 2] * PSCALE;
            sp[t][3] = nuv[j * 9 + 0];
            sp[t][4] = nuv[j * 9 + 1];
            sp[t][5] = nuv[j * 9 + 2];
            sp[t][6] = 0.f; sp[t][7] = 0.f;
        }
        if (t < 384) {
            const int r = t / 12, c = t - r * 12;
            (&sA2P[0][0])[t] = (c < 8) ? A2[r * 8 + c] : ((c == 8) ? B2[r] : 0.f);
        }
        if (t < CUTSN) {
            sA1B1[t][0] = A1[t * 3 + 0];
            sA1B1[t][1] = A1[t * 3 + 1];
            sA1B1[t][2] = A1[t * 3 + 2];
            sA1B1[t][3] = B1[t];
        }
    }

    /* ---- i-side (per lane) ---- */
    const float pix = points[i * 3 + 0] * PSCALE;
    const float piy = points[i * 3 + 1] * PSCALE;
    const float piz = points[i * 3 + 2] * PSCALE;
    float nv[9];
#pragma unroll
    for (int k = 0; k < 9; ++k) nv[k] = nuv[i * 9 + k];

    float acc[HDIM];
#pragma unroll
    for (int h = 0; h < HDIM; ++h) acc[h] = 0.f;

    __syncthreads();

    const int jw0 = wave * 16;
#pragma unroll 1
    for (int cc = 0; cc < 4; ++cc) {
        const int jb4 = jw0 + cc * 4;

        /* phase A: geometry + first layer for 4 j's; fold window into u
         * (w > 0, so w*relu(y) = relu(w*y)) */
        float X[4][3], wq[4];
#pragma unroll
        for (int q = 0; q < 4; ++q) {
            const int jl = jb4 + q;
            const float4 p0 = *(const float4*)&sp[jl][0];
            const float4 p1 = *(const float4*)&sp[jl][4];
            const float dx = p0.x - pix, dy = p0.y - piy, dz = p0.z - piz;
            const float sq = fmaf(dx, dx, fmaf(dy, dy, dz * dz));
            const float dot = fmaf(nv[0], p0.w, fmaf(nv[1], p1.x, nv[2] * p1.y));
            const float tt = 2.f - dot;
            wq[q] = __expf(-sq * tt * tt);
            X[q][0] = fmaf(nv[0], dx, fmaf(nv[1], dy, nv[2] * dz));
            X[q][1] = fmaf(nv[3], dx, fmaf(nv[4], dy, nv[5] * dz));
            X[q][2] = fmaf(nv[6], dx, fmaf(nv[7], dy, nv[8] * dz));
        }
        float u[4][CUTSN];
#pragma unroll
        for (int c = 0; c < CUTSN; ++c) {
            const float4 ab = *(const float4*)&sA1B1[c][0];
#pragma unroll
            for (int q = 0; q < 4; ++q) {
                float v = fmaf(X[q][0], ab.x,
                          fmaf(X[q][1], ab.y,
                          fmaf(X[q][2], ab.z, ab.w)));
                u[q][c] = wq[q] * fmaxf(v, 0.f);     /* window folded in */
            }
        }

        /* phase B: 8->32 matvec + fin accumulate, h outer */
#pragma unroll
        for (int h = 0; h < HDIM; ++h) {
            const float4 a2a = *(const float4*)&sA2P[h][0];
            const float4 a2b = *(const float4*)&sA2P[h][4];
            const float  b2h = sA2P[h][8];
            const float4 f4  = *(const float4*)&sfT[h][jb4];
            const float fv[4] = { f4.x, f4.y, f4.z, f4.w };
            float a = acc[h];
#pragma unroll
            for (int q = 0; q < 4; ++q) {
                float v = fmaf(u[q][0], a2a.x, fmaf(u[q][1], a2a.y,
                          fmaf(u[q][2], a2a.z, fmaf(u[q][3], a2a.w,
                          fmaf(u[q][4], a2b.x, fmaf(u[q][5], a2b.y,
                          fmaf(u[q][6], a2b.z, fmaf(u[q][7], a2b.w,
                               wq[q] * b2h))))))));
                a = fmaf(fmaxf(v, 0.f), fv[q], a);
            }
            acc[h] = a;
        }
    }

    /* ---- cross-wave reduction, 4 fully-unrolled rounds of 8 h ---- */
#pragma unroll
    for (int r4 = 0; r4 < 4; ++r4) {
        const int h0 = r4 * 8;                      /* static after unroll */
        __syncthreads();
#pragma unroll
        for (int c = 0; c < 8; ++c) red[wave][lane][c] = acc[h0 + c];
        __syncthreads();
        {
            const int il = t >> 3, hh = t & 7;      /* 512 cells = 64 i x 8 h */
            float v = 0.f;
#pragma unroll
            for (int w = 0; w < 8; ++w) v += red[w][il][hh];
            atomicAdd(&fout[(blockIdx.y * BI + il) * HDIM + h0 + hh], v);
        }
    }
}

extern "C" void kernel_launch(void* const* d_in, const int* in_sizes, int n_in,
                              void* d_out, int out_size, void* d_ws, size_t ws_size,
                              hipStream_t stream)
{
    const float* points   = (const float*)d_in[0];
    const float* nuv      = (const float*)d_in[1];
    const float* features = (const float*)d_in[2];
    const float* W_in1    = (const float*)d_in[3];
    const float* b_in1    = (const float*)d_in[4];
    const float* W_in2    = (const float*)d_in[5];
    const float* b_in2    = (const float*)d_in[6];
    const float* g_in_w   = (const float*)d_in[7];
    const float* g_in_b   = (const float*)d_in[8];
    const float* A1       = (const float*)d_in[9];
    const float* A2       = (const float*)d_in[10];
    const float* W_out1   = (const float*)d_in[11];
    const float* b_out1   = (const float*)d_in[12];
    const float* W_out2   = (const float*)d_in[13];
    const float* b_out2   = (const float*)d_in[14];
    const float* g_out_w  = (const float*)d_in[15];
    const float* g_out_b  = (const float*)d_in[16];
    const float* B1       = (const float*)d_in[17];
    const float* B2       = (const float*)d_in[18];

    float* ws    = (float*)d_ws;
    float* t2a   = ws;               /* N*H = 65536 */
    float* fin   = ws + 65536;
    float* t2b   = ws + 131072;
    float* fout  = ws + 196608;
    float* part1 = ws + 262144;      /* 64 floats */
    float* part2 = ws + 262208;      /* 64 floats */
    float* out   = (float*)d_out;

    /* net_in (+stats partials), then normalize -> fin and zero fout */
    net2_kernel<IDIM><<<dim3(NPTS / 256), dim3(256), 0, stream>>>(
        features, W_in1, b_in1, W_in2, b_in2, t2a, part1);
    gn_apply_kernel<<<dim3(NPTS * HDIM / 256), dim3(256), 0, stream>>>(
        t2a, part1, g_in_w, g_in_b, fin, fout);

    /* all-pairs interaction */
    pairwise_kernel<<<dim3(NPTS / BJ, NPTS / BI), dim3(PWT), 0, stream>>>(
        points, nuv, A1, B1, A2, B2, fin, fout);

    /* net_out (+stats partials), then final normalize -> out */
    net2_kernel<HDIM><<<dim3(NPTS / 256), dim3(256), 0, stream>>>(
        fout, W_out1, b_out1, W_out2, b_out2, t2b, part2);
    gn_apply_kernel<<<dim3(NPTS * HDIM / 256), dim3(256), 0, stream>>>(
        t2b, part2, g_out_w, g_out_b, out, nullptr);
}

// Round 5
// 171.143 us; speedup vs baseline: 5.4859x; 1.7470x over previous
//
#include <hip/hip_runtime.h>
#include <hip/hip_bf16.h>

#define NPTS   2048
#define IDIM   16
#define HDIM   32
#define CUTSN  8
#define EPSV   1e-5f
#define PSCALE 0.07856742013183862f   /* 1/(sqrt(2)*9) */

#define BI 64      /* i-rows per block (one per lane) */
#define BJ 128     /* j-cols per block */
#define PWT 512    /* threads: 8 waves, each wave owns 16 j */

__device__ __forceinline__ float leaky(float x) { return x >= 0.f ? x : 0.2f * x; }

/* ------- two-layer MLP (per-row) + per-block GroupNorm partial sums -------
 * 8 blocks x 256 threads, one row per thread. partials layout (64 floats):
 * rows 0..3 = group sums (partials[g*8 + block]), rows 4..7 = group sumsq. */
template <int K>
__global__ __launch_bounds__(256) void net2_kernel(
    const float* __restrict__ xin,
    const float* __restrict__ W1, const float* __restrict__ b1,
    const float* __restrict__ W2, const float* __restrict__ b2,
    float* __restrict__ out, float* __restrict__ partials)
{
    const int t = threadIdx.x;
    const int i = blockIdx.x * 256 + t;
    float x[K];
#pragma unroll
    for (int k = 0; k < K; ++k) x[k] = xin[i * K + k];

    float y[HDIM];
#pragma unroll
    for (int h = 0; h < HDIM; ++h) {
        float v = b1[h];
#pragma unroll
        for (int k = 0; k < K; ++k) v = fmaf(x[k], W1[h * K + k], v);
        y[h] = leaky(v);
    }
    float ps[4]  = {0.f, 0.f, 0.f, 0.f};
    float pss[4] = {0.f, 0.f, 0.f, 0.f};
#pragma unroll
    for (int h = 0; h < HDIM; ++h) {
        float v = b2[h];
#pragma unroll
        for (int k = 0; k < HDIM; ++k) v = fmaf(y[k], W2[h * HDIM + k], v);
        v = leaky(v);
        out[i * HDIM + h] = v;
        const int g = h >> 3;                 /* compile-time after unroll */
        ps[g] += v; pss[g] = fmaf(v, v, pss[g]);
    }
    /* wave reduce the 8 partials */
#pragma unroll
    for (int off = 32; off; off >>= 1) {
#pragma unroll
        for (int g = 0; g < 4; ++g) {
            ps[g]  += __shfl_down(ps[g],  off, 64);
            pss[g] += __shfl_down(pss[g], off, 64);
        }
    }
    __shared__ float lred[4][8];
    const int wv = t >> 6, ln = t & 63;
    if (ln == 0) {
#pragma unroll
        for (int g = 0; g < 4; ++g) { lred[wv][g] = ps[g]; lred[wv][4 + g] = pss[g]; }
    }
    __syncthreads();
    if (t < 8) {
        const float v = lred[0][t] + lred[1][t] + lred[2][t] + lred[3][t];
        partials[t * 8 + blockIdx.x] = v;
    }
}

/* ------- GroupNorm apply: reduces the 8 block-partials inline ------- */
__global__ __launch_bounds__(256) void gn_apply_kernel(
    const float* __restrict__ x, const float* __restrict__ partials,
    const float* __restrict__ gw, const float* __restrict__ gb,
    float* __restrict__ out, float* __restrict__ zbuf)
{
    const int idx = blockIdx.x * 256 + threadIdx.x;   /* < NPTS*HDIM */
    const int c = idx & (HDIM - 1);
    const int g = c >> 3;
    float s = 0.f, q = 0.f;
#pragma unroll
    for (int b = 0; b < 8; ++b) {
        s += partials[g * 8 + b];
        q += partials[32 + g * 8 + b];
    }
    const float inv = 1.f / (8.f * NPTS);
    const float mu = s * inv;
    const float rs = rsqrtf(q * inv - mu * mu + EPSV);
    out[idx] = fmaf((x[idx] - mu) * rs, gw[c], gb[c]);
    if (zbuf) zbuf[idx] = 0.f;
}

/* =================== the N^2 pairwise kernel (LDS-staged) ===================
 * grid (16, 32): x -> 128-j tile, y -> 64-i tile. 512 threads = 8 waves.
 * lane = i; wave w owns j-subrange [w*16, w*16+16), processed in chunks of 4.
 * ALL inner-loop operands live in LDS; j-side reads are wave-uniform ->
 * broadcast ds_read. acc[] / u[] use ONLY compile-time indices (rule #20).
 *
 * launch_bounds(512, 1): min-waves=1/EU -> VGPR cap 256. The default
 * heuristic picked 2 waves/EU (cap 128) and SPILLED acc[] -> 710 MB of
 * scratch HBM traffic = the entire 170 us runtime (round 4).
 * sched_barrier every 8 h: stops the scheduler hoisting all 32 unrolled
 * h-iterations' ds_reads at once (the pressure spike that forced the spill). */
__global__ __launch_bounds__(PWT, 1) void pairwise_kernel(
    const float* __restrict__ points, const float* __restrict__ nuv,
    const float* __restrict__ A1, const float* __restrict__ B1,
    const float* __restrict__ A2, const float* __restrict__ B2,
    const float* __restrict__ fin, float* __restrict__ fout)
{
    const int t    = threadIdx.x;
    const int lane = t & 63;
    const int wave = __builtin_amdgcn_readfirstlane(t >> 6);
    const int i     = blockIdx.y * BI + lane;
    const int jbase = blockIdx.x * BJ;

    /* f-tile transposed: sfT[h][j], padded to 132 so rows stay 16B-aligned */
    __shared__ __align__(16) float sfT[HDIM][132];
    __shared__ __align__(16) float sp[BJ][8];        /* x,y,z,nx,ny,nz,-,- */
    __shared__ __align__(16) float sA2P[HDIM][12];   /* A2 row(8) + B2 + pad */
    __shared__ __align__(16) float sA1B1[CUTSN][4];  /* A1 row(3) + B1 */
    __shared__ float red[8][64][9];                  /* stride 9: conflict-free */

    /* ---- stage ---- */
    {
        const float4* src4 = (const float4*)(fin + jbase * HDIM);
#pragma unroll
        for (int s = 0; s < 2; ++s) {
            const int idx4 = t + s * PWT;            /* < 1024 */
            float4 v = src4[idx4];
            const int flat = idx4 * 4;
            const int j = flat >> 5, h = flat & 31;
            sfT[h + 0][j] = v.x; sfT[h + 1][j] = v.y;
            sfT[h + 2][j] = v.z; sfT[h + 3][j] = v.w;
        }
        if (t < BJ) {
            const int j = jbase + t;
            sp[t][0] = points[j * 3 + 0] * PSCALE;
            sp[t][1] = points[j * 3 + 1] * PSCALE;
            sp[t][2] = points[j * 3 + 2] * PSCALE;
            sp[t][3] = nuv[j * 9 + 0];
            sp[t][4] = nuv[j * 9 + 1];
            sp[t][5] = nuv[j * 9 + 2];
            sp[t][6] = 0.f; sp[t][7] = 0.f;
        }
        if (t < 384) {
            const int r = t / 12, c = t - r * 12;
            (&sA2P[0][0])[t] = (c < 8) ? A2[r * 8 + c] : ((c == 8) ? B2[r] : 0.f);
        }
        if (t < CUTSN) {
            sA1B1[t][0] = A1[t * 3 + 0];
            sA1B1[t][1] = A1[t * 3 + 1];
            sA1B1[t][2] = A1[t * 3 + 2];
            sA1B1[t][3] = B1[t];
        }
    }

    /* ---- i-side (per lane) ---- */
    const float pix = points[i * 3 + 0] * PSCALE;
    const float piy = points[i * 3 + 1] * PSCALE;
    const float piz = points[i * 3 + 2] * PSCALE;
    float nv[9];
#pragma unroll
    for (int k = 0; k < 9; ++k) nv[k] = nuv[i * 9 + k];

    float acc[HDIM];
#pragma unroll
    for (int h = 0; h < HDIM; ++h) acc[h] = 0.f;

    __syncthreads();

    const int jw0 = wave * 16;
#pragma unroll 1
    for (int cc = 0; cc < 4; ++cc) {
        const int jb4 = jw0 + cc * 4;

        /* phase A: geometry + first layer for 4 j's; fold window into u
         * (w > 0, so w*relu(y) = relu(w*y)) */
        float X[4][3], wq[4];
#pragma unroll
        for (int q = 0; q < 4; ++q) {
            const int jl = jb4 + q;
            const float4 p0 = *(const float4*)&sp[jl][0];
            const float4 p1 = *(const float4*)&sp[jl][4];
            const float dx = p0.x - pix, dy = p0.y - piy, dz = p0.z - piz;
            const float sq = fmaf(dx, dx, fmaf(dy, dy, dz * dz));
            const float dot = fmaf(nv[0], p0.w, fmaf(nv[1], p1.x, nv[2] * p1.y));
            const float tt = 2.f - dot;
            wq[q] = __expf(-sq * tt * tt);
            X[q][0] = fmaf(nv[0], dx, fmaf(nv[1], dy, nv[2] * dz));
            X[q][1] = fmaf(nv[3], dx, fmaf(nv[4], dy, nv[5] * dz));
            X[q][2] = fmaf(nv[6], dx, fmaf(nv[7], dy, nv[8] * dz));
        }
        float u[4][CUTSN];
#pragma unroll
        for (int c = 0; c < CUTSN; ++c) {
            const float4 ab = *(const float4*)&sA1B1[c][0];
#pragma unroll
            for (int q = 0; q < 4; ++q) {
                float v = fmaf(X[q][0], ab.x,
                          fmaf(X[q][1], ab.y,
                          fmaf(X[q][2], ab.z, ab.w)));
                u[q][c] = wq[q] * fmaxf(v, 0.f);     /* window folded in */
            }
        }

        /* phase B: 8->32 matvec + fin accumulate, h outer, fenced in
         * groups of 8 h to bound the scheduler's load-hoist window */
#pragma unroll
        for (int hg = 0; hg < 4; ++hg) {
#pragma unroll
            for (int hl = 0; hl < 8; ++hl) {
                const int h = hg * 8 + hl;           /* compile-time */
                const float4 a2a = *(const float4*)&sA2P[h][0];
                const float4 a2b = *(const float4*)&sA2P[h][4];
                const float  b2h = sA2P[h][8];
                const float4 f4  = *(const float4*)&sfT[h][jb4];
                const float fv[4] = { f4.x, f4.y, f4.z, f4.w };
                float a = acc[h];
#pragma unroll
                for (int q = 0; q < 4; ++q) {
                    float v = fmaf(u[q][0], a2a.x, fmaf(u[q][1], a2a.y,
                              fmaf(u[q][2], a2a.z, fmaf(u[q][3], a2a.w,
                              fmaf(u[q][4], a2b.x, fmaf(u[q][5], a2b.y,
                              fmaf(u[q][6], a2b.z, fmaf(u[q][7], a2b.w,
                                   wq[q] * b2h))))))));
                    a = fmaf(fmaxf(v, 0.f), fv[q], a);
                }
                acc[h] = a;
            }
            __builtin_amdgcn_sched_barrier(0);       /* fence: bound pressure */
        }
    }

    /* ---- cross-wave reduction, 4 fully-unrolled rounds of 8 h ---- */
#pragma unroll
    for (int r4 = 0; r4 < 4; ++r4) {
        const int h0 = r4 * 8;                      /* static after unroll */
        __syncthreads();
#pragma unroll
        for (int c = 0; c < 8; ++c) red[wave][lane][c] = acc[h0 + c];
        __syncthreads();
        {
            const int il = t >> 3, hh = t & 7;      /* 512 cells = 64 i x 8 h */
            float v = 0.f;
#pragma unroll
            for (int w = 0; w < 8; ++w) v += red[w][il][hh];
            atomicAdd(&fout[(blockIdx.y * BI + il) * HDIM + h0 + hh], v);
        }
    }
}

extern "C" void kernel_launch(void* const* d_in, const int* in_sizes, int n_in,
                              void* d_out, int out_size, void* d_ws, size_t ws_size,
                              hipStream_t stream)
{
    const float* points   = (const float*)d_in[0];
    const float* nuv      = (const float*)d_in[1];
    const float* features = (const float*)d_in[2];
    const float* W_in1    = (const float*)d_in[3];
    const float* b_in1    = (const float*)d_in[4];
    const float* W_in2    = (const float*)d_in[5];
    const float* b_in2    = (const float*)d_in[6];
    const float* g_in_w   = (const float*)d_in[7];
    const float* g_in_b   = (const float*)d_in[8];
    const float* A1       = (const float*)d_in[9];
    const float* A2       = (const float*)d_in[10];
    const float* W_out1   = (const float*)d_in[11];
    const float* b_out1   = (const float*)d_in[12];
    const float* W_out2   = (const float*)d_in[13];
    const float* b_out2   = (const float*)d_in[14];
    const float* g_out_w  = (const float*)d_in[15];
    const float* g_out_b  = (const float*)d_in[16];
    const float* B1       = (const float*)d_in[17];
    const float* B2       = (const float*)d_in[18];

    float* ws    = (float*)d_ws;
    float* t2a   = ws;               /* N*H = 65536 */
    float* fin   = ws + 65536;
    float* t2b   = ws + 131072;
    float* fout  = ws + 196608;
    float* part1 = ws + 262144;      /* 64 floats */
    float* part2 = ws + 262208;      /* 64 floats */
    float* out   = (float*)d_out;

    /* net_in (+stats partials), then normalize -> fin and zero fout */
    net2_kernel<IDIM><<<dim3(NPTS / 256), dim3(256), 0, stream>>>(
        features, W_in1, b_in1, W_in2, b_in2, t2a, part1);
    gn_apply_kernel<<<dim3(NPTS * HDIM / 256), dim3(256), 0, stream>>>(
        t2a, part1, g_in_w, g_in_b, fin, fout);

    /* all-pairs interaction */
    pairwise_kernel<<<dim3(NPTS / BJ, NPTS / BI), dim3(PWT), 0, stream>>>(
        points, nuv, A1, B1, A2, B2, fin, fout);

    /* net_out (+stats partials), then final normalize -> out */
    net2_kernel<HDIM><<<dim3(NPTS / 256), dim3(256), 0, stream>>>(
        fout, W_out1, b_out1, W_out2, b_out2, t2b, part2);
    gn_apply_kernel<<<dim3(NPTS * HDIM / 256), dim3(256), 0, stream>>>(
        t2b, part2, g_out_w, g_out_b, out, nullptr);
}